// Round 1
// baseline (3800.269 us; speedup 1.0000x reference)
//
#include <hip/hip_runtime.h>
#include <math.h>

// ---------------- constants describing the tensor-product structure ----------
#define NPATH 11
#define MUL 128
#define SROW 1152   // x1 / out row length
#define SAMP 2      // samples per block

__device__ __constant__ int c_L1[NPATH] = {0,0,0,1,1,1,1,2,2,2,2};
__device__ __constant__ int c_L2[NPATH] = {0,1,2,0,1,1,2,0,1,2,2};
__device__ __constant__ int c_L3[NPATH] = {0,1,2,1,0,2,1,2,1,0,2};
// flat offsets of each path's w3j tensor (sizes (2l1+1)(2l2+1)(2l3+1))
__device__ __constant__ int c_W3OFF[NPATH+1] = {0,1,10,35,44,53,98,143,168,213,238,363};
// flat offsets of each path's M matrix (sizes (2l1+1)(2l3+1))
__device__ __constant__ int c_MOFF[NPATH+1]  = {0,1,4,9,18,21,36,45,70,85,90,115};
// flat offsets of each path's A columns (sizes (2l3+1))
__device__ __constant__ int c_QOFF[NPATH+1]  = {0,1,4,9,12,13,18,21,26,29,30,35};
__device__ __constant__ int c_X1OFF[3] = {0,128,512};
__device__ __constant__ int c_X2OFF[3] = {0,1,4};

// path weight normalization: sqrt((2lo+1)/(128*paths_to_lo))
#define PW0 0.05103103630798288f
#define PW1 0.07654655446197431f
#define PW2 0.09882117688026186f

// ---------------- Wigner 3j on device (faithful port of the reference) -------
__device__ double dfact(int n) {
    double r = 1.0;
    for (int i = 2; i <= n; ++i) r *= (double)i;
    return r;
}

__device__ double su2_cg(int j1, int m1, int j2, int m2, int j3, int m3) {
    if (m3 != m1 + m2) return 0.0;
    int vmin = -j1 + j2 + m3;
    if (-j1 + m1 > vmin) vmin = -j1 + m1;
    if (0 > vmin) vmin = 0;
    int vmax = j2 + j3 + m1;
    if (j3 - j1 + j2 < vmax) vmax = j3 - j1 + j2;
    if (j3 + m3 < vmax) vmax = j3 + m3;
    if (vmax < vmin) return 0.0;
    double pref = (2.0 * j3 + 1.0) *
        (dfact(j3 + j1 - j2) * dfact(j3 - j1 + j2) * dfact(j1 + j2 - j3) *
         dfact(j3 + m3) * dfact(j3 - m3)) /
        (dfact(j1 + j2 + j3 + 1) * dfact(j1 - m1) * dfact(j1 + m1) *
         dfact(j2 - m2) * dfact(j2 + m2));
    double S = 0.0;
    for (int v = vmin; v <= vmax; ++v) {
        double sgn = ((v + j2 + m2) & 1) ? -1.0 : 1.0;
        S += sgn * (dfact(j2 + j3 + m1 - v) * dfact(j1 - m1 + v)) /
             (dfact(v) * dfact(j3 - j1 + j2 - v) * dfact(j3 + m3 - v) *
              dfact(v + j1 - j2 - m3));
    }
    return sqrt(pref) * S;
}

// q: real->complex change of basis, e3nn convention. qr/qi are 5x5 (n=2l+1 used)
__device__ void build_q(int l, double qr[5][5], double qi[5][5]) {
    for (int r = 0; r < 5; ++r)
        for (int c = 0; c < 5; ++c) { qr[r][c] = 0.0; qi[r][c] = 0.0; }
    double s = 1.0 / sqrt(2.0);
    for (int m = -l; m < 0; ++m) {
        qr[l + m][l - m] = s;      // q[l+m, l+|m|] = 1/sqrt2
        qi[l + m][l + m] = -s;     // q[l+m, l-|m|] = -i/sqrt2
    }
    qr[l][l] = 1.0;
    for (int m = 1; m <= l; ++m) {
        double sg = (m & 1) ? -1.0 : 1.0;
        qr[l + m][l + m] = sg * s;  // (-1)^m/sqrt2
        qi[l + m][l - m] = sg * s;  // i(-1)^m/sqrt2
    }
    // multiply by (-i)^l
    double fr, fi;
    if (l == 0)      { fr = 1.0;  fi = 0.0; }
    else if (l == 1) { fr = 0.0;  fi = -1.0; }
    else             { fr = -1.0; fi = 0.0; }
    for (int r = 0; r < 5; ++r)
        for (int c = 0; c < 5; ++c) {
            double a = qr[r][c], b = qi[r][c];
            qr[r][c] = a * fr - b * fi;
            qi[r][c] = a * fi + b * fr;
        }
}

__global__ void w3j_init_kernel(float* __restrict__ w3) {
    int p = threadIdx.x;
    if (p >= NPATH) return;
    int l1 = c_L1[p], l2 = c_L2[p], l3 = c_L3[p];
    int n1 = 2 * l1 + 1, n2 = 2 * l2 + 1, n3 = 2 * l3 + 1;

    double C[5][5][5];
    for (int i = 0; i < n1; ++i)
        for (int k = 0; k < n2; ++k)
            for (int n = 0; n < n3; ++n) C[i][k][n] = 0.0;
    for (int m1 = -l1; m1 <= l1; ++m1)
        for (int m2 = -l2; m2 <= l2; ++m2) {
            int m3 = m1 + m2;
            if (m3 >= -l3 && m3 <= l3)
                C[m1 + l1][m2 + l2][m3 + l3] = su2_cg(l1, m1, l2, m2, l3, m3);
        }

    double q1r[5][5], q1i[5][5], q2r[5][5], q2i[5][5], q3r[5][5], q3i[5][5];
    build_q(l1, q1r, q1i);
    build_q(l2, q2r, q2i);
    build_q(l3, q3r, q3i);

    double Ccr[5][5][5], Cci[5][5][5];
    for (int j = 0; j < n1; ++j)
        for (int l = 0; l < n2; ++l)
            for (int m = 0; m < n3; ++m) {
                double ar = 0.0, ai = 0.0;
                for (int i = 0; i < n1; ++i)
                    for (int k = 0; k < n2; ++k) {
                        double t1r = q1r[i][j], t1i = q1i[i][j];
                        double t2r = q2r[k][l], t2i = q2i[k][l];
                        double tr = t1r * t2r - t1i * t2i;
                        double ti = t1r * t2i + t1i * t2r;
                        for (int n = 0; n < n3; ++n) {
                            double c = C[i][k][n];
                            if (c == 0.0) continue;
                            // conj(Q3[n][m])
                            double pr = q3r[n][m], pi = -q3i[n][m];
                            ar += c * (tr * pr - ti * pi);
                            ai += c * (tr * pi + ti * pr);
                        }
                    }
                Ccr[j][l][m] = ar;
                Cci[j][l][m] = ai;
            }

    double nr = 0.0, ni = 0.0;
    for (int j = 0; j < n1; ++j)
        for (int l = 0; l < n2; ++l)
            for (int m = 0; m < n3; ++m) {
                nr += Ccr[j][l][m] * Ccr[j][l][m];
                ni += Cci[j][l][m] * Cci[j][l][m];
            }
    nr = sqrt(nr);
    ni = sqrt(ni);
    bool useR = (nr >= ni);
    double norm = useR ? nr : ni;

    float* outp = w3 + c_W3OFF[p];
    for (int j = 0; j < n1; ++j)
        for (int l = 0; l < n2; ++l)
            for (int m = 0; m < n3; ++m) {
                double v = (useR ? Ccr[j][l][m] : Cci[j][l][m]) / norm;
                outp[(j * n2 + l) * n3 + m] = (float)v;
            }
}

// ---------------- main tensor-product kernel --------------------------------
__global__ __launch_bounds__(256) void fctp_kernel(
    const float* __restrict__ x1, const float* __restrict__ x2,
    const float* __restrict__ weight, const float* __restrict__ w3,
    float* __restrict__ out, int N)
{
    __shared__ float sW3[363];
    __shared__ float sM[SAMP][115];
    __shared__ float sX1[SAMP][SROW];
    __shared__ float sA[SAMP][128][35];

    const int tid = threadIdx.x;
    const int n0 = blockIdx.x * SAMP;

    // stage w3j + x1 tile
    for (int i = tid; i < 363; i += 256) sW3[i] = w3[i];
    for (int i = tid; i < SAMP * SROW; i += 256) {
        int s = i / SROW, c = i % SROW;
        int n = n0 + s;
        sX1[s][c] = (n < N) ? x1[(size_t)n * SROW + c] : 0.0f;
    }
    __syncthreads();

    // M_p[i,k] = sum_j w3j[i,j,k] * x2[j]
    for (int e = tid; e < SAMP * 115; e += 256) {
        int s = e / 115, m = e % 115;
        int p = 0;
        #pragma unroll
        for (int t = 0; t < NPATH; ++t)
            if (m >= c_MOFF[t + 1]) p = t + 1;
        int r = m - c_MOFF[p];
        int n2 = 2 * c_L2[p] + 1, n3 = 2 * c_L3[p] + 1;
        int i = r / n3, k = r % n3;
        float acc = 0.0f;
        int n = n0 + s;
        if (n < N) {
            const float* Cp = &sW3[c_W3OFF[p]];
            const float* x2p = &x2[(size_t)n * 9 + c_X2OFF[c_L2[p]]];
            for (int j = 0; j < n2; ++j)
                acc += Cp[(i * n2 + j) * n3 + k] * x2p[j];
        }
        sM[s][m] = acc;
    }
    __syncthreads();

    // A_p[u,k] = sum_i x1_l1[u,i] * M_p[i,k]
    for (int e = tid; e < SAMP * 128 * 35; e += 256) {
        int s = e / (128 * 35);
        int r = e % (128 * 35);
        int u = r / 35, q = r % 35;
        int p = 0;
        #pragma unroll
        for (int t = 0; t < NPATH; ++t)
            if (q >= c_QOFF[t + 1]) p = t + 1;
        int k = q - c_QOFF[p];
        int l1 = c_L1[p];
        int n1 = 2 * l1 + 1, n3 = 2 * c_L3[p] + 1;
        const float* x1p = &sX1[s][c_X1OFF[l1] + u * n1];
        const float* Mp = &sM[s][c_MOFF[p]];
        float acc = 0.0f;
        for (int i = 0; i < n1; ++i) acc += x1p[i] * Mp[i * n3 + k];
        sA[s][u][q] = acc;
    }
    __syncthreads();

    // out_lo[w,k] = PW_lo * sum_p sum_u W_p[u,w] * A_p[u,k]
    const int w = tid & 127;
    const int g = tid >> 7;

    if (g == 0) {
        // lo=0 (paths 0,4,9) and lo=1 (paths 1,3,6,8)
        float acc[SAMP][4];
        #pragma unroll
        for (int s = 0; s < SAMP; ++s)
            #pragma unroll
            for (int k = 0; k < 4; ++k) acc[s][k] = 0.0f;
        for (int u = 0; u < 128; ++u) {
            float w0 = weight[0 * 16384 + u * 128 + w];
            float w4 = weight[4 * 16384 + u * 128 + w];
            float w9 = weight[9 * 16384 + u * 128 + w];
            float w1 = weight[1 * 16384 + u * 128 + w];
            float w3v = weight[3 * 16384 + u * 128 + w];
            float w6 = weight[6 * 16384 + u * 128 + w];
            float w8 = weight[8 * 16384 + u * 128 + w];
            #pragma unroll
            for (int s = 0; s < SAMP; ++s) {
                const float* A = sA[s][u];
                acc[s][0] += w0 * A[0] + w4 * A[12] + w9 * A[29];
                acc[s][1] += w1 * A[1] + w3v * A[9]  + w6 * A[18] + w8 * A[26];
                acc[s][2] += w1 * A[2] + w3v * A[10] + w6 * A[19] + w8 * A[27];
                acc[s][3] += w1 * A[3] + w3v * A[11] + w6 * A[20] + w8 * A[28];
            }
        }
        for (int s = 0; s < SAMP; ++s) {
            int n = n0 + s;
            if (n >= N) break;
            float* o = &out[(size_t)n * SROW];
            o[w] = PW0 * acc[s][0];
            o[128 + w * 3 + 0] = PW1 * acc[s][1];
            o[128 + w * 3 + 1] = PW1 * acc[s][2];
            o[128 + w * 3 + 2] = PW1 * acc[s][3];
        }
    } else {
        // lo=2 (paths 2,5,7,10)
        float acc[SAMP][5];
        #pragma unroll
        for (int s = 0; s < SAMP; ++s)
            #pragma unroll
            for (int k = 0; k < 5; ++k) acc[s][k] = 0.0f;
        for (int u = 0; u < 128; ++u) {
            float w2  = weight[2 * 16384 + u * 128 + w];
            float w5  = weight[5 * 16384 + u * 128 + w];
            float w7  = weight[7 * 16384 + u * 128 + w];
            float w10 = weight[10 * 16384 + u * 128 + w];
            #pragma unroll
            for (int s = 0; s < SAMP; ++s) {
                const float* A = sA[s][u];
                #pragma unroll
                for (int k = 0; k < 5; ++k)
                    acc[s][k] += w2 * A[4 + k] + w5 * A[13 + k] +
                                 w7 * A[21 + k] + w10 * A[30 + k];
            }
        }
        for (int s = 0; s < SAMP; ++s) {
            int n = n0 + s;
            if (n >= N) break;
            float* o = &out[(size_t)n * SROW];
            #pragma unroll
            for (int k = 0; k < 5; ++k)
                o[512 + w * 5 + k] = PW2 * acc[s][k];
        }
    }
}

// ---------------- launch -----------------------------------------------------
extern "C" void kernel_launch(void* const* d_in, const int* in_sizes, int n_in,
                              void* d_out, int out_size, void* d_ws, size_t ws_size,
                              hipStream_t stream) {
    const float* x1 = (const float*)d_in[0];
    const float* x2 = (const float*)d_in[1];
    const float* wt = (const float*)d_in[2];
    float* out = (float*)d_out;
    float* w3 = (float*)d_ws;

    int N = in_sizes[0] / SROW;

    hipLaunchKernelGGL(w3j_init_kernel, dim3(1), dim3(64), 0, stream, w3);

    int blocks = (N + SAMP - 1) / SAMP;
    hipLaunchKernelGGL(fctp_kernel, dim3(blocks), dim3(256), 0, stream,
                       x1, x2, wt, w3, out, N);
}

// Round 2
// 972.652 us; speedup vs baseline: 3.9071x; 3.9071x over previous
//
#include <hip/hip_runtime.h>
#include <math.h>

// ---------------- constants describing the tensor-product structure ----------
#define NPATH 11
#define MUL 128
#define SROW 1152   // x1 / out row length
#define SAMP 2      // samples per block

__device__ __constant__ int c_MOFF[NPATH+1]  = {0,1,4,9,18,21,36,45,70,85,90,115};
__device__ __constant__ int c_QOFF[NPATH+1]  = {0,1,4,9,12,13,18,21,26,29,30,35};
__device__ __constant__ int c_W3OFF_d[NPATH+1] = {0,1,10,35,44,53,98,143,168,213,238,363};
__device__ __constant__ int c_L1[NPATH] = {0,0,0,1,1,1,1,2,2,2,2};
__device__ __constant__ int c_L2[NPATH] = {0,1,2,0,1,1,2,0,1,2,2};
__device__ __constant__ int c_L3[NPATH] = {0,1,2,1,0,2,1,2,1,0,2};
__device__ __constant__ int c_X1OFF[3] = {0,128,512};
__device__ __constant__ int c_X2OFF[3] = {0,1,4};

// path weight normalization: sqrt((2lo+1)/(128*paths_to_lo))
#define PW0 0.05103103630798288f
#define PW1 0.07654655446197431f
#define PW2 0.09882117688026186f

// ================= compile-time Wigner 3j (exact port of reference) =========
namespace w3c {

constexpr double fact(int n) {
    double r = 1.0;
    for (int i = 2; i <= n; ++i) r *= (double)i;
    return r;
}

constexpr double csqrt(double x) {
    if (x <= 0.0) return 0.0;
    double g = x < 1.0 ? 1.0 : x;
    for (int i = 0; i < 100; ++i) g = 0.5 * (g + x / g);
    return g;
}

constexpr double su2_cg(int j1, int m1, int j2, int m2, int j3, int m3) {
    if (m3 != m1 + m2) return 0.0;
    int vmin = -j1 + j2 + m3;
    if (-j1 + m1 > vmin) vmin = -j1 + m1;
    if (0 > vmin) vmin = 0;
    int vmax = j2 + j3 + m1;
    if (j3 - j1 + j2 < vmax) vmax = j3 - j1 + j2;
    if (j3 + m3 < vmax) vmax = j3 + m3;
    if (vmax < vmin) return 0.0;
    double pref = (2.0 * j3 + 1.0) *
        (fact(j3 + j1 - j2) * fact(j3 - j1 + j2) * fact(j1 + j2 - j3) *
         fact(j3 + m3) * fact(j3 - m3)) /
        (fact(j1 + j2 + j3 + 1) * fact(j1 - m1) * fact(j1 + m1) *
         fact(j2 - m2) * fact(j2 + m2));
    double S = 0.0;
    for (int v = vmin; v <= vmax; ++v) {
        double sgn = ((v + j2 + m2) & 1) ? -1.0 : 1.0;
        S += sgn * (fact(j2 + j3 + m1 - v) * fact(j1 - m1 + v)) /
             (fact(v) * fact(j3 - j1 + j2 - v) * fact(j3 + m3 - v) *
              fact(v + j1 - j2 - m3));
    }
    return csqrt(pref) * S;
}

struct Q { double re[5][5]; double im[5][5]; };

constexpr Q build_q(int l) {
    Q q{};
    double s = csqrt(0.5);
    for (int m = -l; m < 0; ++m) {
        q.re[l + m][l - m] = s;     // q[l+m, l+|m|] = 1/sqrt2
        q.im[l + m][l + m] = -s;    // q[l+m, l-|m|] = -i/sqrt2
    }
    q.re[l][l] = 1.0;
    for (int m = 1; m <= l; ++m) {
        double sg = (m & 1) ? -1.0 : 1.0;
        q.re[l + m][l + m] = sg * s;  // (-1)^m/sqrt2
        q.im[l + m][l - m] = sg * s;  // i(-1)^m/sqrt2
    }
    // multiply by (-i)^l : l=0 -> 1, l=1 -> -i, l=2 -> -1
    double fr = 1.0, fi = 0.0;
    if (l == 1) { fr = 0.0; fi = -1.0; }
    else if (l == 2) { fr = -1.0; fi = 0.0; }
    for (int r = 0; r < 5; ++r)
        for (int c = 0; c < 5; ++c) {
            double a = q.re[r][c], b = q.im[r][c];
            q.re[r][c] = a * fr - b * fi;
            q.im[r][c] = a * fi + b * fr;
        }
    return q;
}

struct PathW { float v[125]; };

constexpr PathW make_path(int l1, int l2, int l3) {
    int n1 = 2 * l1 + 1, n2 = 2 * l2 + 1, n3 = 2 * l3 + 1;
    double C[5][5][5] = {};
    for (int m1 = -l1; m1 <= l1; ++m1)
        for (int m2 = -l2; m2 <= l2; ++m2) {
            int m3 = m1 + m2;
            if (m3 >= -l3 && m3 <= l3)
                C[m1 + l1][m2 + l2][m3 + l3] = su2_cg(l1, m1, l2, m2, l3, m3);
        }
    Q q1 = build_q(l1), q2 = build_q(l2), q3 = build_q(l3);

    double Cr[5][5][5] = {}, Ci[5][5][5] = {};
    for (int j = 0; j < n1; ++j)
        for (int l = 0; l < n2; ++l)
            for (int m = 0; m < n3; ++m) {
                double ar = 0.0, ai = 0.0;
                for (int i = 0; i < n1; ++i)
                    for (int k = 0; k < n2; ++k) {
                        double t1r = q1.re[i][j], t1i = q1.im[i][j];
                        double t2r = q2.re[k][l], t2i = q2.im[k][l];
                        double tr = t1r * t2r - t1i * t2i;
                        double ti = t1r * t2i + t1i * t2r;
                        for (int n = 0; n < n3; ++n) {
                            double c = C[i][k][n];
                            if (c == 0.0) continue;
                            double pr = q3.re[n][m], pi = -q3.im[n][m]; // conj(Q3[n][m])
                            ar += c * (tr * pr - ti * pi);
                            ai += c * (tr * pi + ti * pr);
                        }
                    }
                Cr[j][l][m] = ar;
                Ci[j][l][m] = ai;
            }

    double nr = 0.0, ni = 0.0;
    for (int j = 0; j < n1; ++j)
        for (int l = 0; l < n2; ++l)
            for (int m = 0; m < n3; ++m) {
                nr += Cr[j][l][m] * Cr[j][l][m];
                ni += Ci[j][l][m] * Ci[j][l][m];
            }
    nr = csqrt(nr);
    ni = csqrt(ni);
    bool useR = (nr >= ni);
    double norm = useR ? nr : ni;

    PathW out{};
    int idx = 0;
    for (int j = 0; j < n1; ++j)
        for (int l = 0; l < n2; ++l)
            for (int m = 0; m < n3; ++m)
                out.v[idx++] = (float)((useR ? Cr[j][l][m] : Ci[j][l][m]) / norm);
    return out;
}

// each path is its own top-level constexpr evaluation (step-budget safety)
constexpr PathW P0  = make_path(0,0,0);
constexpr PathW P1  = make_path(0,1,1);
constexpr PathW P2  = make_path(0,2,2);
constexpr PathW P3  = make_path(1,0,1);
constexpr PathW P4  = make_path(1,1,0);
constexpr PathW P5  = make_path(1,1,2);
constexpr PathW P6  = make_path(1,2,1);
constexpr PathW P7  = make_path(2,0,2);
constexpr PathW P8  = make_path(2,1,1);
constexpr PathW P9  = make_path(2,2,0);
constexpr PathW P10 = make_path(2,2,2);

struct W3All { float v[363]; };

constexpr W3All make_all() {
    W3All a{};
    const PathW* ps[11] = {&P0,&P1,&P2,&P3,&P4,&P5,&P6,&P7,&P8,&P9,&P10};
    const int off[12] = {0,1,10,35,44,53,98,143,168,213,238,363};
    for (int p = 0; p < 11; ++p) {
        int n = off[p+1] - off[p];
        for (int i = 0; i < n; ++i) a.v[off[p] + i] = ps[p]->v[i];
    }
    return a;
}

} // namespace w3c

__device__ __constant__ w3c::W3All c_W3 = w3c::make_all();

// ---------------- main tensor-product kernel --------------------------------
__global__ __launch_bounds__(256) void fctp_kernel(
    const float* __restrict__ x1, const float* __restrict__ x2,
    const float* __restrict__ weight,
    float* __restrict__ out, int N)
{
    __shared__ float sW3[363];
    __shared__ float sM[SAMP][115];
    __shared__ float sX1[SAMP][SROW];
    __shared__ float sA[SAMP][128][35];

    const int tid = threadIdx.x;
    const int n0 = blockIdx.x * SAMP;

    // stage w3j + x1 tile
    for (int i = tid; i < 363; i += 256) sW3[i] = c_W3.v[i];
    for (int i = tid; i < SAMP * SROW; i += 256) {
        int s = i / SROW, c = i % SROW;
        int n = n0 + s;
        sX1[s][c] = (n < N) ? x1[(size_t)n * SROW + c] : 0.0f;
    }
    __syncthreads();

    // M_p[i,k] = sum_j w3j[i,j,k] * x2[j]
    for (int e = tid; e < SAMP * 115; e += 256) {
        int s = e / 115, m = e % 115;
        int p = 0;
        #pragma unroll
        for (int t = 0; t < NPATH; ++t)
            if (m >= c_MOFF[t + 1]) p = t + 1;
        int r = m - c_MOFF[p];
        int n2 = 2 * c_L2[p] + 1, n3 = 2 * c_L3[p] + 1;
        int i = r / n3, k = r % n3;
        float acc = 0.0f;
        int n = n0 + s;
        if (n < N) {
            const float* Cp = &sW3[c_W3OFF_d[p]];
            const float* x2p = &x2[(size_t)n * 9 + c_X2OFF[c_L2[p]]];
            for (int j = 0; j < n2; ++j)
                acc += Cp[(i * n2 + j) * n3 + k] * x2p[j];
        }
        sM[s][m] = acc;
    }
    __syncthreads();

    // A_p[u,k] = sum_i x1_l1[u,i] * M_p[i,k]
    for (int e = tid; e < SAMP * 128 * 35; e += 256) {
        int s = e / (128 * 35);
        int r = e % (128 * 35);
        int u = r / 35, q = r % 35;
        int p = 0;
        #pragma unroll
        for (int t = 0; t < NPATH; ++t)
            if (q >= c_QOFF[t + 1]) p = t + 1;
        int k = q - c_QOFF[p];
        int l1 = c_L1[p];
        int n1 = 2 * l1 + 1, n3 = 2 * c_L3[p] + 1;
        const float* x1p = &sX1[s][c_X1OFF[l1] + u * n1];
        const float* Mp = &sM[s][c_MOFF[p]];
        float acc = 0.0f;
        for (int i = 0; i < n1; ++i) acc += x1p[i] * Mp[i * n3 + k];
        sA[s][u][q] = acc;
    }
    __syncthreads();

    // out_lo[w,k] = PW_lo * sum_p sum_u W_p[u,w] * A_p[u,k]
    const int w = tid & 127;
    const int g = tid >> 7;

    if (g == 0) {
        // lo=0 (paths 0,4,9) and lo=1 (paths 1,3,6,8)
        float acc[SAMP][4];
        #pragma unroll
        for (int s = 0; s < SAMP; ++s)
            #pragma unroll
            for (int k = 0; k < 4; ++k) acc[s][k] = 0.0f;
        for (int u = 0; u < 128; ++u) {
            float w0 = weight[0 * 16384 + u * 128 + w];
            float w4 = weight[4 * 16384 + u * 128 + w];
            float w9 = weight[9 * 16384 + u * 128 + w];
            float w1 = weight[1 * 16384 + u * 128 + w];
            float w3v = weight[3 * 16384 + u * 128 + w];
            float w6 = weight[6 * 16384 + u * 128 + w];
            float w8 = weight[8 * 16384 + u * 128 + w];
            #pragma unroll
            for (int s = 0; s < SAMP; ++s) {
                const float* A = sA[s][u];
                acc[s][0] += w0 * A[0] + w4 * A[12] + w9 * A[29];
                acc[s][1] += w1 * A[1] + w3v * A[9]  + w6 * A[18] + w8 * A[26];
                acc[s][2] += w1 * A[2] + w3v * A[10] + w6 * A[19] + w8 * A[27];
                acc[s][3] += w1 * A[3] + w3v * A[11] + w6 * A[20] + w8 * A[28];
            }
        }
        for (int s = 0; s < SAMP; ++s) {
            int n = n0 + s;
            if (n >= N) break;
            float* o = &out[(size_t)n * SROW];
            o[w] = PW0 * acc[s][0];
            o[128 + w * 3 + 0] = PW1 * acc[s][1];
            o[128 + w * 3 + 1] = PW1 * acc[s][2];
            o[128 + w * 3 + 2] = PW1 * acc[s][3];
        }
    } else {
        // lo=2 (paths 2,5,7,10)
        float acc[SAMP][5];
        #pragma unroll
        for (int s = 0; s < SAMP; ++s)
            #pragma unroll
            for (int k = 0; k < 5; ++k) acc[s][k] = 0.0f;
        for (int u = 0; u < 128; ++u) {
            float w2  = weight[2 * 16384 + u * 128 + w];
            float w5  = weight[5 * 16384 + u * 128 + w];
            float w7  = weight[7 * 16384 + u * 128 + w];
            float w10 = weight[10 * 16384 + u * 128 + w];
            #pragma unroll
            for (int s = 0; s < SAMP; ++s) {
                const float* A = sA[s][u];
                #pragma unroll
                for (int k = 0; k < 5; ++k)
                    acc[s][k] += w2 * A[4 + k] + w5 * A[13 + k] +
                                 w7 * A[21 + k] + w10 * A[30 + k];
            }
        }
        for (int s = 0; s < SAMP; ++s) {
            int n = n0 + s;
            if (n >= N) break;
            float* o = &out[(size_t)n * SROW];
            #pragma unroll
            for (int k = 0; k < 5; ++k)
                o[512 + w * 5 + k] = PW2 * acc[s][k];
        }
    }
}

// ---------------- launch -----------------------------------------------------
extern "C" void kernel_launch(void* const* d_in, const int* in_sizes, int n_in,
                              void* d_out, int out_size, void* d_ws, size_t ws_size,
                              hipStream_t stream) {
    const float* x1 = (const float*)d_in[0];
    const float* x2 = (const float*)d_in[1];
    const float* wt = (const float*)d_in[2];
    float* out = (float*)d_out;

    int N = in_sizes[0] / SROW;

    int blocks = (N + SAMP - 1) / SAMP;
    hipLaunchKernelGGL(fctp_kernel, dim3(blocks), dim3(256), 0, stream,
                       x1, x2, wt, out, N);
}

// Round 4
// 547.306 us; speedup vs baseline: 6.9436x; 1.7772x over previous
//
#include <hip/hip_runtime.h>
#include <math.h>

// ---------------- tensor-product structure ----------------------------------
#define NPATH 11
#define SROW 1152       // x1 / out row length
#define SAMP 16         // samples per block
#define NTHREADS 512    // 8 waves; wave wt owns output channels [wt*16, wt*16+16)

constexpr int H_L1[11]  = {0,0,0,1,1,1,1,2,2,2,2};
constexpr int H_L2[11]  = {0,1,2,0,1,1,2,0,1,2,2};
constexpr int H_LO[11]  = {0,1,2,1,0,2,1,2,1,0,2};
constexpr int H_N1[11]  = {1,1,1,3,3,3,3,5,5,5,5};
constexpr int H_N2[11]  = {1,3,5,1,3,3,5,1,3,5,5};
constexpr int H_N3[11]  = {1,3,5,3,1,5,3,5,3,1,5};
constexpr int H_PIB[11] = {0,1,2,3,6,9,12,15,20,25,30};  // prefix sum of N1
constexpr int H_MOFF[12]  = {0,1,4,9,18,21,36,45,70,85,90,115};
constexpr int H_W3OFF[12] = {0,1,10,35,44,53,98,143,168,213,238,363};
constexpr int H_X2OFF[3]  = {0,1,4};
constexpr int H_CBASE[3]  = {0,1,4};   // x1T column base per l1
constexpr int H_KCB[3]    = {0,1,4};   // output k-column base per lo
constexpr float H_PW[3] = {0.05103103630798288f, 0.07654655446197431f, 0.09882117688026186f};

// ================= compile-time Wigner 3j (exact port of reference) =========
namespace w3c {

constexpr double fact(int n) {
    double r = 1.0;
    for (int i = 2; i <= n; ++i) r *= (double)i;
    return r;
}

constexpr double csqrt(double x) {
    if (x <= 0.0) return 0.0;
    double g = x < 1.0 ? 1.0 : x;
    for (int i = 0; i < 100; ++i) g = 0.5 * (g + x / g);
    return g;
}

constexpr double su2_cg(int j1, int m1, int j2, int m2, int j3, int m3) {
    if (m3 != m1 + m2) return 0.0;
    int vmin = -j1 + j2 + m3;
    if (-j1 + m1 > vmin) vmin = -j1 + m1;
    if (0 > vmin) vmin = 0;
    int vmax = j2 + j3 + m1;
    if (j3 - j1 + j2 < vmax) vmax = j3 - j1 + j2;
    if (j3 + m3 < vmax) vmax = j3 + m3;
    if (vmax < vmin) return 0.0;
    double pref = (2.0 * j3 + 1.0) *
        (fact(j3 + j1 - j2) * fact(j3 - j1 + j2) * fact(j1 + j2 - j3) *
         fact(j3 + m3) * fact(j3 - m3)) /
        (fact(j1 + j2 + j3 + 1) * fact(j1 - m1) * fact(j1 + m1) *
         fact(j2 - m2) * fact(j2 + m2));
    double S = 0.0;
    for (int v = vmin; v <= vmax; ++v) {
        double sgn = ((v + j2 + m2) & 1) ? -1.0 : 1.0;
        S += sgn * (fact(j2 + j3 + m1 - v) * fact(j1 - m1 + v)) /
             (fact(v) * fact(j3 - j1 + j2 - v) * fact(j3 + m3 - v) *
              fact(v + j1 - j2 - m3));
    }
    return csqrt(pref) * S;
}

struct Q { double re[5][5]; double im[5][5]; };

constexpr Q build_q(int l) {
    Q q{};
    double s = csqrt(0.5);
    for (int m = -l; m < 0; ++m) {
        q.re[l + m][l - m] = s;
        q.im[l + m][l + m] = -s;
    }
    q.re[l][l] = 1.0;
    for (int m = 1; m <= l; ++m) {
        double sg = (m & 1) ? -1.0 : 1.0;
        q.re[l + m][l + m] = sg * s;
        q.im[l + m][l - m] = sg * s;
    }
    double fr = 1.0, fi = 0.0;
    if (l == 1) { fr = 0.0; fi = -1.0; }
    else if (l == 2) { fr = -1.0; fi = 0.0; }
    for (int r = 0; r < 5; ++r)
        for (int c = 0; c < 5; ++c) {
            double a = q.re[r][c], b = q.im[r][c];
            q.re[r][c] = a * fr - b * fi;
            q.im[r][c] = a * fi + b * fr;
        }
    return q;
}

struct PathW { float v[125]; };

constexpr PathW make_path(int l1, int l2, int l3) {
    int n1 = 2 * l1 + 1, n2 = 2 * l2 + 1, n3 = 2 * l3 + 1;
    double C[5][5][5] = {};
    for (int m1 = -l1; m1 <= l1; ++m1)
        for (int m2 = -l2; m2 <= l2; ++m2) {
            int m3 = m1 + m2;
            if (m3 >= -l3 && m3 <= l3)
                C[m1 + l1][m2 + l2][m3 + l3] = su2_cg(l1, m1, l2, m2, l3, m3);
        }
    Q q1 = build_q(l1), q2 = build_q(l2), q3 = build_q(l3);

    double Cr[5][5][5] = {}, Ci[5][5][5] = {};
    for (int j = 0; j < n1; ++j)
        for (int l = 0; l < n2; ++l)
            for (int m = 0; m < n3; ++m) {
                double ar = 0.0, ai = 0.0;
                for (int i = 0; i < n1; ++i)
                    for (int k = 0; k < n2; ++k) {
                        double t1r = q1.re[i][j], t1i = q1.im[i][j];
                        double t2r = q2.re[k][l], t2i = q2.im[k][l];
                        double tr = t1r * t2r - t1i * t2i;
                        double ti = t1r * t2i + t1i * t2r;
                        for (int n = 0; n < n3; ++n) {
                            double c = C[i][k][n];
                            if (c == 0.0) continue;
                            double pr = q3.re[n][m], pi = -q3.im[n][m];
                            ar += c * (tr * pr - ti * pi);
                            ai += c * (tr * pi + ti * pr);
                        }
                    }
                Cr[j][l][m] = ar;
                Ci[j][l][m] = ai;
            }

    double nr = 0.0, ni = 0.0;
    for (int j = 0; j < n1; ++j)
        for (int l = 0; l < n2; ++l)
            for (int m = 0; m < n3; ++m) {
                nr += Cr[j][l][m] * Cr[j][l][m];
                ni += Ci[j][l][m] * Ci[j][l][m];
            }
    nr = csqrt(nr);
    ni = csqrt(ni);
    bool useR = (nr >= ni);
    double norm = useR ? nr : ni;

    PathW out{};
    int idx = 0;
    for (int j = 0; j < n1; ++j)
        for (int l = 0; l < n2; ++l)
            for (int m = 0; m < n3; ++m)
                out.v[idx++] = (float)((useR ? Cr[j][l][m] : Ci[j][l][m]) / norm);
    return out;
}

constexpr PathW P0  = make_path(0,0,0);
constexpr PathW P1  = make_path(0,1,1);
constexpr PathW P2  = make_path(0,2,2);
constexpr PathW P3  = make_path(1,0,1);
constexpr PathW P4  = make_path(1,1,0);
constexpr PathW P5  = make_path(1,1,2);
constexpr PathW P6  = make_path(1,2,1);
constexpr PathW P7  = make_path(2,0,2);
constexpr PathW P8  = make_path(2,1,1);
constexpr PathW P9  = make_path(2,2,0);
constexpr PathW P10 = make_path(2,2,2);

struct W3All { float v[363]; };

constexpr W3All make_all() {
    W3All a{};
    const PathW* ps[11] = {&P0,&P1,&P2,&P3,&P4,&P5,&P6,&P7,&P8,&P9,&P10};
    for (int p = 0; p < 11; ++p) {
        int n = H_W3OFF[p+1] - H_W3OFF[p];
        for (int i = 0; i < n; ++i) a.v[H_W3OFF[p] + i] = ps[p]->v[i];
    }
    return a;
}

} // namespace w3c

__device__ __constant__ w3c::W3All c_W3 = w3c::make_all();

typedef float f32x4 __attribute__((ext_vector_type(4)));

// ---------------- main kernel (fp32 VALU GEMM; bisection + speed step) -------
// Same structure as round 3: acc[pi][r] layout per lane:
//   n = lane&15 (sample), w = wt*16 + (lane>>4)*4 + r (output channel)
// LDS: sXf[9][16][133] fp32 (x1 transposed), sM35[16*175] fp32.
// sOut (output staging) aliases sXf after a barrier.

__global__ __launch_bounds__(NTHREADS, 1) void fctp_kernel(
    const float* __restrict__ x1, const float* __restrict__ x2,
    const float* __restrict__ weight,
    float* __restrict__ out, int N)
{
    __shared__ float sXf[9][16][133];   // 76608 B
    __shared__ float sM35[16 * 175];    // 11200 B

    const int tid  = threadIdx.x;
    const int lane = tid & 63;
    const int wt   = tid >> 6;
    const int n0   = blockIdx.x * SAMP;

    // ---- stage X1 transposed (fp32): sXf[col][n][u] ----
    for (int e = tid; e < SAMP * SROW; e += NTHREADS) {
        int n = e / SROW, c = e % SROW;
        int col, u;
        if (c < 128)       { col = 0;           u = c; }
        else if (c < 512)  { int rr = c - 128;  u = rr / 3; col = 1 + rr % 3; }
        else               { int rr = c - 512;  u = rr / 5; col = 4 + rr % 5; }
        float f = (n0 + n < N) ? x1[(size_t)(n0 + n) * SROW + c] : 0.0f;
        sXf[col][n][u] = f;
    }

    // ---- stage PW * M_p[n,i,k] into sM35 at [(n*35+pi)*5 + k] ----
    for (int e = tid; e < SAMP * 115; e += NTHREADS) {
        int n = e / 115, m = e % 115;
        float val = 0.0f;
        int pi5 = 0;
        #pragma unroll
        for (int p = 0; p < NPATH; ++p) {
            if (m >= H_MOFF[p] && m < H_MOFF[p + 1]) {
                const int n2 = H_N2[p], n3 = H_N3[p];
                int rr = m - H_MOFF[p];
                int i = rr / n3, k = rr % n3;
                if (n0 + n < N) {
                    const float* Cp  = c_W3.v + H_W3OFF[p];
                    const float* x2p = x2 + (size_t)(n0 + n) * 9 + H_X2OFF[H_L2[p]];
                    float a = 0.0f;
                    #pragma unroll
                    for (int j = 0; j < n2; ++j)
                        a += Cp[(i * n2 + j) * n3 + k] * x2p[j];
                    val = H_PW[H_LO[p]] * a;
                }
                pi5 = (H_PIB[p] + i) * 5 + k;
            }
        }
        sM35[n * 175 + pi5] = val;
    }
    __syncthreads();

    // ---- fp32 GEMM: acc[pi][r] = sum_u W_p[u, w(r)] * X[col(p,i)][n][u] ----
    const int n     = lane & 15;
    const int qq    = lane >> 4;
    const int wbase = wt * 16 + qq * 4;

    float acc[35][4];
    #pragma unroll
    for (int pi = 0; pi < 35; ++pi)
        #pragma unroll
        for (int r = 0; r < 4; ++r) acc[pi][r] = 0.0f;

    for (int u = 0; u < 128; ++u) {
        float xv[9];
        #pragma unroll
        for (int col = 0; col < 9; ++col) xv[col] = sXf[col][n][u];

        #pragma unroll
        for (int p = 0; p < NPATH; ++p) {
            f32x4 wv = *(const f32x4*)&weight[(size_t)p * 16384 + u * 128 + wbase];
            #pragma unroll
            for (int i = 0; i < H_N1[p]; ++i) {
                const float xvi = xv[H_CBASE[H_L1[p]] + i];
                const int pi = H_PIB[p] + i;
                #pragma unroll
                for (int r = 0; r < 4; ++r)
                    acc[pi][r] += wv[r] * xvi;
            }
        }
    }

    // ---- combine: ov[r][kc] = sum_{pi,k} acc[pi][r] * sM35[n][pi][k] ----
    float ov[4][9];
    #pragma unroll
    for (int r = 0; r < 4; ++r)
        #pragma unroll
        for (int j = 0; j < 9; ++j) ov[r][j] = 0.0f;

    #pragma unroll
    for (int p = 0; p < NPATH; ++p) {
        #pragma unroll
        for (int i = 0; i < H_N1[p]; ++i) {
            const int pi = H_PIB[p] + i;
            #pragma unroll
            for (int k = 0; k < H_N3[p]; ++k) {
                const float mv = sM35[n * 175 + pi * 5 + k];
                const int kc = H_KCB[H_LO[p]] + k;
                #pragma unroll
                for (int r = 0; r < 4; ++r)
                    ov[r][kc] += acc[pi][r] * mv;
            }
        }
    }

    // ---- write to sOut (aliases sXf) then coalesced global store ----
    __syncthreads();
    float* sOut = (float*)&sXf[0][0][0];   // [16][1153]
    #pragma unroll
    for (int r = 0; r < 4; ++r) {
        const int w = wbase + r;
        float* so = &sOut[n * 1153];
        so[w] = ov[r][0];
        #pragma unroll
        for (int k = 0; k < 3; ++k) so[128 + w * 3 + k] = ov[r][1 + k];
        #pragma unroll
        for (int k = 0; k < 5; ++k) so[512 + w * 5 + k] = ov[r][4 + k];
    }
    __syncthreads();

    for (int e = tid; e < SAMP * SROW; e += NTHREADS) {
        int nn = e / SROW, c = e % SROW;
        if (n0 + nn < N) out[(size_t)(n0 + nn) * SROW + c] = sOut[nn * 1153 + c];
    }
}

// ---------------- launch -----------------------------------------------------
extern "C" void kernel_launch(void* const* d_in, const int* in_sizes, int n_in,
                              void* d_out, int out_size, void* d_ws, size_t ws_size,
                              hipStream_t stream) {
    const float* x1 = (const float*)d_in[0];
    const float* x2 = (const float*)d_in[1];
    const float* wt = (const float*)d_in[2];
    float* out = (float*)d_out;

    int N = in_sizes[0] / SROW;

    int blocks = (N + SAMP - 1) / SAMP;
    hipLaunchKernelGGL(fctp_kernel, dim3(blocks), dim3(NTHREADS), 0, stream,
                       x1, x2, wt, out, N);
}